// Round 7
// baseline (34.783 us; speedup 1.0000x reference)
//
#include <hip/hip_runtime.h>
#include <math.h>

#define NCLS 80
#define NANCH 3
#define NB 16
#define TPB 512
#define CELLS 8

// Module-global completion counter. Initialized to 0 at module load; the
// last block of every launch resets it to 0, so every call (correctness
// call and each graph replay) starts from 0 deterministically.
__device__ int g_counter = 0;

__device__ __forceinline__ float softplusf(float x) {
    return fmaxf(x, 0.0f) + log1pf(expf(-fabsf(x)));
}

// Single kernel, single node.
//  blocks [0, nblk_obj): objectness sweep, 8 cells/thread -> partial[12]
//  blocks [nblk_obj, nblk_tot): 8 target-waves/block -> partials[0..11]
// Partial layout (13 floats/block): lv*4+{0:cnt,1:lbox,2:lobjc,3:lcls}, [12]=obj
// Last-arriving block reduces all partials and writes out[0].
__global__ void __launch_bounds__(TPB)
k_one(const float* __restrict__ p0, const float* __restrict__ p1,
      const float* __restrict__ p2, int n0, int n1, int n2,
      float inv0, float inv1, float inv2,
      const float* __restrict__ targets, int T,
      const float* __restrict__ anchors,
      float* __restrict__ ws, float* __restrict__ out,
      int nblk_obj, int nblk_tot) {
    const int lane = threadIdx.x & 63;
    const int wv   = threadIdx.x >> 6;

    float v[13];
#pragma unroll
    for (int k = 0; k < 13; ++k) v[k] = 0.0f;

    if ((int)blockIdx.x < nblk_obj) {
        // ---------------- objectness background sweep ----------------
        const int total = n0 + n1 + n2;
        int base = (blockIdx.x * TPB + threadIdx.x) * CELLS;
        float obj = 0.0f;
#pragma unroll
        for (int u = 0; u < CELLS; ++u) {
            int idx = base + u;
            if (idx < total) {
                const float* p; int i2; float inv;
                if (idx < n0)           { p = p0; i2 = idx;           inv = inv0; }
                else if (idx < n0 + n1) { p = p1; i2 = idx - n0;      inv = inv1; }
                else                    { p = p2; i2 = idx - n0 - n1; inv = inv2; }
                obj += softplusf(p[(size_t)i2 * 85 + 4]) * inv;
            }
        }
        v[12] = obj;
    } else {
        // ---------------- matched-target waves ----------------
        int w = (blockIdx.x - nblk_obj) * (TPB / 64) + wv;
        const int perlvl = NANCH * T;
        if (w < 3 * perlvl) {
            int yi = w / perlvl;
            int e = w - yi * perlvl;
            int a = e / T, ti = e - a * T;
            const float* p = (yi == 0) ? p0 : (yi == 1) ? p1 : p2;
            int W = (yi == 0) ? 80 : (yi == 1) ? 40 : 20;
            int H = W;
            float stride = (yi == 0) ? 8.0f : (yi == 1) ? 16.0f : 32.0f;
            float Ninv = 1.0f / (float)(NB * NANCH * H * W);
            const float* tg = targets + (size_t)ti * 6;
            float tx = tg[2] * (float)W, ty = tg[3] * (float)H;
            float tw = tg[4] * (float)W, th = tg[5] * (float)H;
            float aw = anchors[yi * 6 + a * 2 + 0] / stride;
            float ah = anchors[yi * 6 + a * 2 + 1] / stride;
            float rw = tw / aw, rh = th / ah;
            float rmax = fmaxf(fmaxf(rw, 1.0f / rw), fmaxf(rh, 1.0f / rh));
            if (rmax < 4.0f) {
                int b = (int)tg[0], c = (int)tg[1];
                int ii = (int)floorf(tx), jj = (int)floorf(ty);
                int gi = min(max(ii, 0), W - 1), gj = min(max(jj, 0), H - 1);
                const float* ps = p + ((size_t)((b * NANCH + a) * H + gj) * W + gi) * 85;
                // lane-parallel class BCE: sum_j softplus(s_j) - s_c
                float cl = softplusf(ps[5 + lane]);
                if (lane < NCLS - 64) cl += softplusf(ps[5 + 64 + lane]);
                float cnt = 0.0f, lbox = 0.0f, lobjc = 0.0f;
                if (lane == 0) {
                    cnt = 1.0f;
                    float tbx = tx - (float)ii, tby = ty - (float)jj;
                    float s4 = ps[4];
                    float px = 1.0f / (1.0f + expf(-ps[0]));
                    float py = 1.0f / (1.0f + expf(-ps[1]));
                    float pw = expf(ps[2]) * aw;
                    float ph = expf(ps[3]) * ah;
                    float b1x1 = px - pw * 0.5f, b1x2 = px + pw * 0.5f;
                    float b1y1 = py - ph * 0.5f, b1y2 = py + ph * 0.5f;
                    float b2x1 = tbx - tw * 0.5f, b2x2 = tbx + tw * 0.5f;
                    float b2y1 = tby - th * 0.5f, b2y2 = tby + th * 0.5f;
                    float iw = fmaxf(fminf(b1x2, b2x2) - fmaxf(b1x1, b2x1), 0.0f);
                    float ih = fmaxf(fminf(b1y2, b2y2) - fmaxf(b1y1, b2y1), 0.0f);
                    float inter = iw * ih;
                    float uni = pw * ph + tw * th - inter + 1e-9f;
                    float iou = inter / uni;
                    lbox = 1.0f - iou;
                    lobjc = -s4 * fmaxf(iou, 0.0f) * Ninv;  // bce(x,z)-bce(x,0)
                    cl -= ps[5 + c];
                }
                if (yi == 0)      { v[0] = cnt; v[1] = lbox; v[2]  = lobjc; v[3]  = cl; }
                else if (yi == 1) { v[4] = cnt; v[5] = lbox; v[6]  = lobjc; v[7]  = cl; }
                else              { v[8] = cnt; v[9] = lbox; v[10] = lobjc; v[11] = cl; }
            }
        }
    }

    // ---------------- uniform block reduce of 13 partials ----------------
#pragma unroll
    for (int o = 32; o > 0; o >>= 1) {
#pragma unroll
        for (int k = 0; k < 13; ++k) v[k] += __shfl_down(v[k], o, 64);
    }
    __shared__ float smem[TPB / 64][13];
    __shared__ int s_last;
    if (lane == 0) {
#pragma unroll
        for (int k = 0; k < 13; ++k) smem[wv][k] = v[k];
    }
    __syncthreads();
    if (threadIdx.x < 13) {
        float s = 0.0f;
#pragma unroll
        for (int i = 0; i < TPB / 64; ++i) s += smem[i][threadIdx.x];
        __hip_atomic_store(&ws[(size_t)blockIdx.x * 13 + threadIdx.x], s,
                           __ATOMIC_RELAXED, __HIP_MEMORY_SCOPE_AGENT);
    }
    __syncthreads();
    if (threadIdx.x == 0) {
        __threadfence();
        int old = __hip_atomic_fetch_add(&g_counter, 1, __ATOMIC_ACQ_REL,
                                         __HIP_MEMORY_SCOPE_AGENT);
        s_last = (old == nblk_tot - 1) ? 1 : 0;
    }
    __syncthreads();
    if (!s_last) return;

    // ---------------- last block: final reduce + combine ----------------
    __threadfence();
    float acc[13];
#pragma unroll
    for (int k = 0; k < 13; ++k) acc[k] = 0.0f;
    for (int b = threadIdx.x; b < nblk_tot; b += TPB) {
#pragma unroll
        for (int k = 0; k < 13; ++k)
            acc[k] += __hip_atomic_load(&ws[(size_t)b * 13 + k],
                                        __ATOMIC_RELAXED, __HIP_MEMORY_SCOPE_AGENT);
    }
#pragma unroll
    for (int o = 32; o > 0; o >>= 1) {
#pragma unroll
        for (int k = 0; k < 13; ++k) acc[k] += __shfl_down(acc[k], o, 64);
    }
    __syncthreads();
    if (lane == 0) {
#pragma unroll
        for (int k = 0; k < 13; ++k) smem[wv][k] = acc[k];
    }
    __syncthreads();
    if (threadIdx.x == 0) {
        float tot[13];
#pragma unroll
        for (int k = 0; k < 13; ++k) {
            float s = 0.0f;
#pragma unroll
            for (int i = 0; i < TPB / 64; ++i) s += smem[i][k];
            tot[k] = s;
        }
        float res = tot[12];
#pragma unroll
        for (int lv = 0; lv < 3; ++lv) {
            float nv = fmaxf(tot[lv * 4 + 0], 1.0f);
            res += tot[lv * 4 + 1] / nv + tot[lv * 4 + 3] / (nv * (float)NCLS)
                 + tot[lv * 4 + 2];
        }
        out[0] = res;
        __hip_atomic_store(&g_counter, 0, __ATOMIC_RELAXED,
                           __HIP_MEMORY_SCOPE_AGENT);
    }
}

extern "C" void kernel_launch(void* const* d_in, const int* in_sizes, int n_in,
                              void* d_out, int out_size, void* d_ws, size_t ws_size,
                              hipStream_t stream) {
    const float* p0 = (const float*)d_in[0];
    const float* p1 = (const float*)d_in[1];
    const float* p2 = (const float*)d_in[2];
    const float* targets = (const float*)d_in[3];
    const float* anchors = (const float*)d_in[4];
    float* out = (float*)d_out;
    float* wsp = (float*)d_ws;

    int n0 = in_sizes[0] / 85;
    int n1 = in_sizes[1] / 85;
    int n2 = in_sizes[2] / 85;
    int T  = in_sizes[3] / 6;

    int total = n0 + n1 + n2;
    int nblk_obj = (total + TPB * CELLS - 1) / (TPB * CELLS);   // 99
    int nwaves = 3 * NANCH * T;                                  // 1800
    int nblk_tgt = (nwaves + (TPB / 64) - 1) / (TPB / 64);       // 225
    int nblk_tot = nblk_obj + nblk_tgt;                          // 324

    k_one<<<nblk_tot, TPB, 0, stream>>>(
        p0, p1, p2, n0, n1, n2,
        1.0f / (float)n0, 1.0f / (float)n1, 1.0f / (float)n2,
        targets, T, anchors, wsp, out, nblk_obj, nblk_tot);
}

// Round 8
// 22.564 us; speedup vs baseline: 1.5415x; 1.5415x over previous
//
#include <hip/hip_runtime.h>
#include <math.h>

#define NCLS 80
#define NANCH 3
#define NB 16
#define TPB 512
#define OBJ_BLOCKS 50
#define OBJ_CELLS 16
#define TGT_BLOCKS 45          // 360 waves

// Module-load-initialized accumulators. The last-arriving block of every
// launch resets them to 0, so each call (correctness + every graph replay)
// starts from a clean state deterministically. No memset node needed.
__device__ float g_accum  = 0.0f;
__device__ int  g_counter = 0;

__device__ __forceinline__ float softplusf(float x) {
    return fmaxf(x, 0.0f) + log1pf(expf(-fabsf(x)));
}

// Single node. Blocks [0,OBJ_BLOCKS): objectness sweep. Blocks
// [OBJ_BLOCKS, OBJ_BLOCKS+TGT_BLOCKS): matched-target waves; each tgt block
// redundantly computes global nv per level from the tiny targets array and
// pre-scales its own contribution. Every block does exactly one relaxed
// fp32 atomicAdd into g_accum + one acq-rel counter bump; the last block
// publishes g_accum to out[0] and resets the globals.
__global__ void __launch_bounds__(TPB)
k_one(const float* __restrict__ p0, const float* __restrict__ p1,
      const float* __restrict__ p2, int n0, int n1, int n2,
      float inv0, float inv1, float inv2,
      const float* __restrict__ targets, int T,
      const float* __restrict__ anchors,
      float* __restrict__ out, int nblk_tot) {
    const int lane = threadIdx.x & 63;
    const int wv   = threadIdx.x >> 6;

    // v: [0..2]=nv cnt, [3..5]=lbox, [6..8]=lcls, [9]=lobj_corr, [12]=obj
    float v[13];
#pragma unroll
    for (int k = 0; k < 13; ++k) v[k] = 0.0f;

    if ((int)blockIdx.x < OBJ_BLOCKS) {
        // ---------------- objectness background sweep ----------------
        const int total = n0 + n1 + n2;
        const int chunk = OBJ_BLOCKS * TPB * OBJ_CELLS;
        float obj = 0.0f;
        for (int base0 = (blockIdx.x * TPB + threadIdx.x) * OBJ_CELLS;
             base0 < total; base0 += chunk) {
#pragma unroll
            for (int u = 0; u < OBJ_CELLS; ++u) {
                int idx = base0 + u;
                if (idx < total) {
                    const float* p; int i2; float inv;
                    if (idx < n0)           { p = p0; i2 = idx;           inv = inv0; }
                    else if (idx < n0 + n1) { p = p1; i2 = idx - n0;      inv = inv1; }
                    else                    { p = p2; i2 = idx - n0 - n1; inv = inv2; }
                    obj += softplusf(p[(size_t)i2 * 85 + 4]) * inv;
                }
            }
        }
        v[12] = obj;
    } else {
        const int perlvl = NANCH * T;
        const int nent = 3 * perlvl;
        // ---- A: redundant global valid-count (targets-only, tiny) ----
        for (int e = threadIdx.x; e < nent; e += TPB) {
            int yi = e / perlvl;
            int rem = e - yi * perlvl;
            int a = rem / T, ti = rem - a * T;
            float Wf = (yi == 0) ? 80.0f : (yi == 1) ? 40.0f : 20.0f;
            float stride = (yi == 0) ? 8.0f : (yi == 1) ? 16.0f : 32.0f;
            const float* tg = targets + (size_t)ti * 6;
            float tw = tg[4] * Wf, th = tg[5] * Wf;
            float aw = anchors[yi * 6 + a * 2 + 0] / stride;
            float ah = anchors[yi * 6 + a * 2 + 1] / stride;
            float rw = tw / aw, rh = th / ah;
            float rmax = fmaxf(fmaxf(rw, 1.0f / rw), fmaxf(rh, 1.0f / rh));
            if (rmax < 4.0f) v[yi] += 1.0f;
        }
        // ---- C: matched-target waves, ~5 entries per wave ----
        const int nwv = TGT_BLOCKS * (TPB / 64);
        for (int e = (blockIdx.x - OBJ_BLOCKS) * (TPB / 64) + wv; e < nent; e += nwv) {
            int yi = e / perlvl;
            int rem = e - yi * perlvl;
            int a = rem / T, ti = rem - a * T;
            const float* p = (yi == 0) ? p0 : (yi == 1) ? p1 : p2;
            int W = (yi == 0) ? 80 : (yi == 1) ? 40 : 20;
            int H = W;
            float stride = (yi == 0) ? 8.0f : (yi == 1) ? 16.0f : 32.0f;
            float Ninv = 1.0f / (float)(NB * NANCH * H * W);
            const float* tg = targets + (size_t)ti * 6;
            float tx = tg[2] * (float)W, ty = tg[3] * (float)H;
            float tw = tg[4] * (float)W, th = tg[5] * (float)H;
            float aw = anchors[yi * 6 + a * 2 + 0] / stride;
            float ah = anchors[yi * 6 + a * 2 + 1] / stride;
            float rw = tw / aw, rh = th / ah;
            float rmax = fmaxf(fmaxf(rw, 1.0f / rw), fmaxf(rh, 1.0f / rh));
            if (rmax < 4.0f) {
                int b = (int)tg[0], c = (int)tg[1];
                int ii = (int)floorf(tx), jj = (int)floorf(ty);
                int gi = min(max(ii, 0), W - 1), gj = min(max(jj, 0), H - 1);
                const float* ps = p + ((size_t)((b * NANCH + a) * H + gj) * W + gi) * 85;
                // lane-parallel class BCE: sum_j softplus(s_j) - s_c
                float cl = softplusf(ps[5 + lane]);
                if (lane < NCLS - 64) cl += softplusf(ps[5 + 64 + lane]);
                if (lane == 0) {
                    float tbx = tx - (float)ii, tby = ty - (float)jj;
                    float s4 = ps[4];
                    float px = 1.0f / (1.0f + expf(-ps[0]));
                    float py = 1.0f / (1.0f + expf(-ps[1]));
                    float pw = expf(ps[2]) * aw;
                    float ph = expf(ps[3]) * ah;
                    float b1x1 = px - pw * 0.5f, b1x2 = px + pw * 0.5f;
                    float b1y1 = py - ph * 0.5f, b1y2 = py + ph * 0.5f;
                    float b2x1 = tbx - tw * 0.5f, b2x2 = tbx + tw * 0.5f;
                    float b2y1 = tby - th * 0.5f, b2y2 = tby + th * 0.5f;
                    float iw = fmaxf(fminf(b1x2, b2x2) - fmaxf(b1x1, b2x1), 0.0f);
                    float ih = fmaxf(fminf(b1y2, b2y2) - fmaxf(b1y1, b2y1), 0.0f);
                    float inter = iw * ih;
                    float uni = pw * ph + tw * th - inter + 1e-9f;
                    float iou = inter / uni;
                    v[3 + yi] += 1.0f - iou;
                    v[9] += -s4 * fmaxf(iou, 0.0f) * Ninv;  // bce(x,z)-bce(x,0)
                    cl -= ps[5 + c];
                }
                v[6 + yi] += cl;
            }
        }
    }

    // ---------------- block reduce ----------------
#pragma unroll
    for (int o = 32; o > 0; o >>= 1) {
#pragma unroll
        for (int k = 0; k < 13; ++k) v[k] += __shfl_down(v[k], o, 64);
    }
    __shared__ float smem[TPB / 64][13];
    if (lane == 0) {
#pragma unroll
        for (int k = 0; k < 13; ++k) smem[wv][k] = v[k];
    }
    __syncthreads();
    if (threadIdx.x == 0) {
        float tot[13];
#pragma unroll
        for (int k = 0; k < 13; ++k) {
            float s = 0.0f;
#pragma unroll
            for (int i = 0; i < TPB / 64; ++i) s += smem[i][k];
            tot[k] = s;
        }
        float contrib;
        if ((int)blockIdx.x < OBJ_BLOCKS) {
            contrib = tot[12];
        } else {
            contrib = tot[9];
#pragma unroll
            for (int lv = 0; lv < 3; ++lv) {
                float nv = fmaxf(tot[lv], 1.0f);
                contrib += tot[3 + lv] / nv + tot[6 + lv] / (nv * (float)NCLS);
            }
        }
        // one scalar atomic per block; release-bump the arrival counter
        __hip_atomic_fetch_add(&g_accum, contrib, __ATOMIC_RELAXED,
                               __HIP_MEMORY_SCOPE_AGENT);
        int old = __hip_atomic_fetch_add(&g_counter, 1, __ATOMIC_ACQ_REL,
                                         __HIP_MEMORY_SCOPE_AGENT);
        if (old == nblk_tot - 1) {
            // last arriver: publish and reset for the next replay
            float res = __hip_atomic_load(&g_accum, __ATOMIC_RELAXED,
                                          __HIP_MEMORY_SCOPE_AGENT);
            out[0] = res;
            __hip_atomic_store(&g_accum, 0.0f, __ATOMIC_RELAXED,
                               __HIP_MEMORY_SCOPE_AGENT);
            __hip_atomic_store(&g_counter, 0, __ATOMIC_RELAXED,
                               __HIP_MEMORY_SCOPE_AGENT);
        }
    }
}

extern "C" void kernel_launch(void* const* d_in, const int* in_sizes, int n_in,
                              void* d_out, int out_size, void* d_ws, size_t ws_size,
                              hipStream_t stream) {
    const float* p0 = (const float*)d_in[0];
    const float* p1 = (const float*)d_in[1];
    const float* p2 = (const float*)d_in[2];
    const float* targets = (const float*)d_in[3];
    const float* anchors = (const float*)d_in[4];
    float* out = (float*)d_out;

    int n0 = in_sizes[0] / 85;
    int n1 = in_sizes[1] / 85;
    int n2 = in_sizes[2] / 85;
    int T  = in_sizes[3] / 6;

    int nblk_tot = OBJ_BLOCKS + TGT_BLOCKS;
    k_one<<<nblk_tot, TPB, 0, stream>>>(
        p0, p1, p2, n0, n1, n2,
        1.0f / (float)n0, 1.0f / (float)n1, 1.0f / (float)n2,
        targets, T, anchors, out, nblk_tot);
}

// Round 9
// 16.970 us; speedup vs baseline: 2.0496x; 1.3296x over previous
//
#include <hip/hip_runtime.h>
#include <math.h>

#define NCLS 80
#define NANCH 3
#define NB 16

__device__ __forceinline__ float softplusf(float x) {
    return fmaxf(x, 0.0f) + log1pf(expf(-fabsf(x)));
}

// Fused kernel, 512 threads/block. (R3 structure — best measured: 17.5 us)
//  blocks [0, nblk_obj): objectness sweep, 8 cells/thread -> wsobj[blk]
//  blocks [nblk_obj, nblk_obj+nblk_tgt): 8 target-waves/block -> wstgt[blk][12]
__global__ void __launch_bounds__(512)
k_fused(const float* __restrict__ p0, const float* __restrict__ p1,
        const float* __restrict__ p2, int n0, int n1, int n2,
        float inv0, float inv1, float inv2,
        const float* __restrict__ targets, int T,
        const float* __restrict__ anchors,
        float* __restrict__ wsobj, int nblk_obj,
        float* __restrict__ wstgt) {
    int lane = threadIdx.x & 63, wv = threadIdx.x >> 6;

    if (blockIdx.x < (unsigned)nblk_obj) {
        // ---------------- objectness background sweep ----------------
        int total = n0 + n1 + n2;
        int base = (blockIdx.x * blockDim.x + threadIdx.x) * 8;
        float v = 0.0f;
#pragma unroll
        for (int u = 0; u < 8; ++u) {
            int idx = base + u;
            if (idx < total) {
                const float* p; int i2; float inv;
                if (idx < n0)           { p = p0; i2 = idx;           inv = inv0; }
                else if (idx < n0 + n1) { p = p1; i2 = idx - n0;      inv = inv1; }
                else                    { p = p2; i2 = idx - n0 - n1; inv = inv2; }
                v += softplusf(p[(size_t)i2 * 85 + 4]) * inv;
            }
        }
#pragma unroll
        for (int o = 32; o > 0; o >>= 1) v += __shfl_down(v, o, 64);
        __shared__ float smem[8];
        if (lane == 0) smem[wv] = v;
        __syncthreads();
        if (threadIdx.x == 0) {
            float s = 0.0f;
#pragma unroll
            for (int i = 0; i < 8; ++i) s += smem[i];
            wsobj[blockIdx.x] = s;
        }
        return;
    }

    // ---------------- matched-target waves ----------------
    int bt = blockIdx.x - nblk_obj;
    int w = bt * 8 + wv;                 // global wave id = (lvl,anchor,tgt)
    int perlvl = NANCH * T;
    int nwaves = 3 * perlvl;
    float cnt = 0.0f, lbox = 0.0f, lobjc = 0.0f, lcls = 0.0f;
    int yi = 0;
    if (w < nwaves) {
        yi = w / perlvl;
        int e = w - yi * perlvl;
        int a = e / T, ti = e - a * T;
        const float* p = (yi == 0) ? p0 : (yi == 1) ? p1 : p2;
        int W = (yi == 0) ? 80 : (yi == 1) ? 40 : 20;
        int H = W;
        float stride = (yi == 0) ? 8.0f : (yi == 1) ? 16.0f : 32.0f;
        float Ninv = 1.0f / (float)(NB * NANCH * H * W);
        const float* tg = targets + (size_t)ti * 6;
        float tx = tg[2] * (float)W, ty = tg[3] * (float)H;
        float tw = tg[4] * (float)W, th = tg[5] * (float)H;
        float aw = anchors[yi * 6 + a * 2 + 0] / stride;
        float ah = anchors[yi * 6 + a * 2 + 1] / stride;
        float rw = tw / aw, rh = th / ah;
        float rmax = fmaxf(fmaxf(rw, 1.0f / rw), fmaxf(rh, 1.0f / rh));
        if (rmax < 4.0f) {
            int b = (int)tg[0], c = (int)tg[1];
            int ii = (int)floorf(tx), jj = (int)floorf(ty);
            int gi = min(max(ii, 0), W - 1), gj = min(max(jj, 0), H - 1);
            const float* ps = p + ((size_t)((b * NANCH + a) * H + gj) * W + gi) * 85;
            // lane-parallel class BCE: sum_j softplus(s_j) - s_c
            float cl = softplusf(ps[5 + lane]);
            if (lane < NCLS - 64) cl += softplusf(ps[5 + 64 + lane]);
            if (lane == 0) {
                cnt = 1.0f;
                float tbx = tx - (float)ii, tby = ty - (float)jj;
                float s4 = ps[4];
                float px = 1.0f / (1.0f + expf(-ps[0]));
                float py = 1.0f / (1.0f + expf(-ps[1]));
                float pw = expf(ps[2]) * aw;
                float ph = expf(ps[3]) * ah;
                float b1x1 = px - pw * 0.5f, b1x2 = px + pw * 0.5f;
                float b1y1 = py - ph * 0.5f, b1y2 = py + ph * 0.5f;
                float b2x1 = tbx - tw * 0.5f, b2x2 = tbx + tw * 0.5f;
                float b2y1 = tby - th * 0.5f, b2y2 = tby + th * 0.5f;
                float iw = fmaxf(fminf(b1x2, b2x2) - fmaxf(b1x1, b2x1), 0.0f);
                float ih = fmaxf(fminf(b1y2, b2y2) - fmaxf(b1y1, b2y1), 0.0f);
                float inter = iw * ih;
                float uni = pw * ph + tw * th - inter + 1e-9f;
                float iou = inter / uni;
                lbox = 1.0f - iou;
                lobjc = -s4 * fmaxf(iou, 0.0f) * Ninv;  // bce(x,z)-bce(x,0)
                cl -= ps[5 + c];
            }
            lcls = cl;
        }
    }
#pragma unroll
    for (int o = 32; o > 0; o >>= 1) lcls += __shfl_down(lcls, o, 64);

    __shared__ float wsum[8][4];
    __shared__ int wlvl[8];
    if (lane == 0) {
        wsum[wv][0] = cnt; wsum[wv][1] = lbox; wsum[wv][2] = lobjc; wsum[wv][3] = lcls;
        wlvl[wv] = yi;
    }
    __syncthreads();
    if (threadIdx.x < 12) {
        int lv = threadIdx.x >> 2, k = threadIdx.x & 3;
        float s = 0.0f;
#pragma unroll
        for (int i = 0; i < 8; ++i)
            if (wlvl[i] == lv) s += wsum[i][k];
        wstgt[(size_t)bt * 12 + threadIdx.x] = s;
    }
}

// Single-block reduction of all partials + final combine. 128 threads.
__global__ void __launch_bounds__(128)
k_final(const float* __restrict__ wstgt, int ntb,
        const float* __restrict__ wsobj, int nob,
        float* __restrict__ out) {
    int tid = threadIdx.x, lane = tid & 63, wv = tid >> 6;
    float acc[12];
#pragma unroll
    for (int k = 0; k < 12; ++k) acc[k] = 0.0f;
    for (int b = tid; b < ntb; b += 128) {
#pragma unroll
        for (int k = 0; k < 12; ++k) acc[k] += wstgt[(size_t)b * 12 + k];
    }
    float objacc = 0.0f;
    for (int b = tid; b < nob; b += 128) objacc += wsobj[b];

#pragma unroll
    for (int o = 32; o > 0; o >>= 1) {
#pragma unroll
        for (int k = 0; k < 12; ++k) acc[k] += __shfl_down(acc[k], o, 64);
        objacc += __shfl_down(objacc, o, 64);
    }
    __shared__ float smem[2][13];
    if (lane == 0) {
#pragma unroll
        for (int k = 0; k < 12; ++k) smem[wv][k] = acc[k];
        smem[wv][12] = objacc;
    }
    __syncthreads();
    if (tid == 0) {
        float tot[13];
#pragma unroll
        for (int k = 0; k < 13; ++k) tot[k] = smem[0][k] + smem[1][k];
        float res = tot[12];
#pragma unroll
        for (int lv = 0; lv < 3; ++lv) {
            float nv = fmaxf(tot[lv * 4 + 0], 1.0f);
            res += tot[lv * 4 + 1] / nv + tot[lv * 4 + 3] / (nv * (float)NCLS)
                 + tot[lv * 4 + 2];
        }
        out[0] = res;
    }
}

extern "C" void kernel_launch(void* const* d_in, const int* in_sizes, int n_in,
                              void* d_out, int out_size, void* d_ws, size_t ws_size,
                              hipStream_t stream) {
    const float* p0 = (const float*)d_in[0];
    const float* p1 = (const float*)d_in[1];
    const float* p2 = (const float*)d_in[2];
    const float* targets = (const float*)d_in[3];
    const float* anchors = (const float*)d_in[4];
    float* out = (float*)d_out;

    int n0 = in_sizes[0] / 85;
    int n1 = in_sizes[1] / 85;
    int n2 = in_sizes[2] / 85;
    int T  = in_sizes[3] / 6;

    int total = n0 + n1 + n2;
    const int THREADS = 512;
    int nblk_obj = (total + THREADS * 8 - 1) / (THREADS * 8);   // 8 cells/thread
    int nwaves = 3 * NANCH * T;
    int nblk_tgt = (nwaves + 7) / 8;                            // 8 waves/block

    float* wstgt = (float*)d_ws;                      // nblk_tgt * 12 floats
    float* wsobj = wstgt + (size_t)nblk_tgt * 12;     // nblk_obj floats

    k_fused<<<nblk_obj + nblk_tgt, THREADS, 0, stream>>>(
        p0, p1, p2, n0, n1, n2,
        1.0f / (float)n0, 1.0f / (float)n1, 1.0f / (float)n2,
        targets, T, anchors, wsobj, nblk_obj, wstgt);

    k_final<<<1, 128, 0, stream>>>(wstgt, nblk_tgt, wsobj, nblk_obj, out);
}